// Round 1
// baseline (2107.493 us; speedup 1.0000x reference)
//
#include <hip/hip_runtime.h>
#include <math.h>

#define S_TOT 2048
#define B_    64
#define E_    256
#define H_    256

// ---------------- Phase 1: xp = A @ W_ih + bias ----------------
// A: [M,256] row-major (sentence chunk flattened), W: [256,256] row-major,
// out: [M,256].  BM=64, BN=64, BK=32, 256 threads, 4x4 microtile/thread.
__global__ __launch_bounds__(256) void gemm_xp(
    const float* __restrict__ A, const float* __restrict__ W,
    const float* __restrict__ bias, float* __restrict__ out)
{
    __shared__ float As[32][68];   // transposed: As[k][m], +4 pad breaks bank strides
    __shared__ float Bs[32][64];   // Bs[k][n]

    const int tid = threadIdx.x;
    const int bm = blockIdx.x * 64;
    const int bn = blockIdx.y * 64;
    const int tx = tid & 15;       // col group
    const int ty = tid >> 4;       // row group

    float acc[4][4] = {};

    // A-tile load mapping: rows ar, ar+32 ; 4 consecutive k each
    const int ar = tid >> 3;            // 0..31
    const int ak = (tid & 7) << 2;      // 0..28
    // B-tile load mapping: rows br, br+16 ; 4 consecutive n each
    const int br = tid >> 4;            // 0..15
    const int bc = (tid & 15) << 2;     // 0..60

    for (int k0 = 0; k0 < E_; k0 += 32) {
        float4 a0 = *(const float4*)&A[(size_t)(bm + ar)      * E_ + k0 + ak];
        float4 a1 = *(const float4*)&A[(size_t)(bm + ar + 32) * E_ + k0 + ak];
        float4 b0 = *(const float4*)&W[(size_t)(k0 + br)      * H_ + bn + bc];
        float4 b1 = *(const float4*)&W[(size_t)(k0 + br + 16) * H_ + bn + bc];

        As[ak+0][ar]    = a0.x; As[ak+1][ar]    = a0.y; As[ak+2][ar]    = a0.z; As[ak+3][ar]    = a0.w;
        As[ak+0][ar+32] = a1.x; As[ak+1][ar+32] = a1.y; As[ak+2][ar+32] = a1.z; As[ak+3][ar+32] = a1.w;
        *(float4*)&Bs[br][bc]      = b0;
        *(float4*)&Bs[br + 16][bc] = b1;
        __syncthreads();

        #pragma unroll
        for (int kk = 0; kk < 32; kk++) {
            const float4 av = *(const float4*)&As[kk][ty << 2];
            const float4 bv = *(const float4*)&Bs[kk][tx << 2];
            acc[0][0] += av.x*bv.x; acc[0][1] += av.x*bv.y; acc[0][2] += av.x*bv.z; acc[0][3] += av.x*bv.w;
            acc[1][0] += av.y*bv.x; acc[1][1] += av.y*bv.y; acc[1][2] += av.y*bv.z; acc[1][3] += av.y*bv.w;
            acc[2][0] += av.z*bv.x; acc[2][1] += av.z*bv.y; acc[2][2] += av.z*bv.z; acc[2][3] += av.z*bv.w;
            acc[3][0] += av.w*bv.x; acc[3][1] += av.w*bv.y; acc[3][2] += av.w*bv.z; acc[3][3] += av.w*bv.w;
        }
        __syncthreads();
    }

    const float4 bb = *(const float4*)&bias[bn + (tx << 2)];
    #pragma unroll
    for (int i = 0; i < 4; i++) {
        float4 o;
        o.x = acc[i][0] + bb.x;
        o.y = acc[i][1] + bb.y;
        o.z = acc[i][2] + bb.z;
        o.w = acc[i][3] + bb.w;
        *(float4*)&out[(size_t)(bm + (ty << 2) + i) * H_ + bn + (tx << 2)] = o;
    }
}

// ---------------- Phase 2: sequential scan, one workgroup per batch ----------
// h_new = tanh(xp[s,b,:] + h @ W_hh).  1024 threads: thread t -> (j = t&255,
// kq = t>>8).  Each thread holds W_hh[kq*64 .. kq*64+63][j] in registers.
__global__ __launch_bounds__(1024) void rnn_scan(
    const float* __restrict__ xp,    // [steps, B, H]
    const float* __restrict__ Whh,   // [H, H]
    float* __restrict__ h,           // [B, H] persistent state (= d_out)
    int steps)
{
    __shared__ float hbuf[H_];
    __shared__ float part[1024];

    const int b = blockIdx.x;
    const int t = threadIdx.x;
    const int j = t & 255;
    const int kq = t >> 8;           // wave-uniform (all 64 lanes share kq)

    float w[64];
    #pragma unroll
    for (int i = 0; i < 64; i++)
        w[i] = Whh[(size_t)(kq * 64 + i) * H_ + j];   // coalesced

    if (t < H_) hbuf[t] = h[b * H_ + t];
    float xpn = (t < H_) ? xp[(size_t)b * H_ + t] : 0.f;   // prefetch step 0
    __syncthreads();

    for (int s = 0; s < steps; s++) {
        const float xpc = xpn;
        if (t < H_ && s + 1 < steps)
            xpn = xp[((size_t)(s + 1) * B_ + b) * H_ + t];  // prefetch next step

        // partial dot over this thread's 64-k slice; hbuf reads are wave-broadcast
        const float4* hv = (const float4*)&hbuf[kq * 64];
        float acc = 0.f;
        #pragma unroll
        for (int i = 0; i < 16; i++) {
            const float4 h4 = hv[i];
            acc += h4.x * w[4*i+0] + h4.y * w[4*i+1]
                 + h4.z * w[4*i+2] + h4.w * w[4*i+3];
        }
        part[t] = acc;
        __syncthreads();

        if (t < H_) {
            float v = xpc + part[j] + part[256 + j] + part[512 + j] + part[768 + j];
            // tanh(v) = 1 - 2/(e^{2v}+1); saturates correctly at +-inf
            float e = __expf(2.f * v);
            hbuf[j] = 1.f - 2.f / (e + 1.f);
        }
        __syncthreads();
    }

    if (t < H_) h[b * H_ + t] = hbuf[t];
}

extern "C" void kernel_launch(void* const* d_in, const int* in_sizes, int n_in,
                              void* d_out, int out_size, void* d_ws, size_t ws_size,
                              hipStream_t stream)
{
    const float* sentence = (const float*)d_in[0];  // [S,B,E]
    const float* h0       = (const float*)d_in[1];  // [B,H]
    const float* W_ih     = (const float*)d_in[2];  // [E,H]
    const float* W_hh     = (const float*)d_in[3];  // [H,H]
    const float* bias     = (const float*)d_in[4];  // [H]
    float* h  = (float*)d_out;                      // h state lives in d_out
    float* xp = (float*)d_ws;                       // chunk buffer [chunk,B,H]

    // Chunk S so the xp staging buffer fits workspace and stays L3-resident.
    int chunk = 512;   // 512*64*256*4 = 33.5 MB
    while ((size_t)chunk * B_ * H_ * sizeof(float) > ws_size && chunk > 64)
        chunk >>= 1;

    hipMemcpyAsync(h, h0, B_ * H_ * sizeof(float), hipMemcpyDeviceToDevice, stream);

    for (int s0 = 0; s0 < S_TOT; s0 += chunk) {
        const int Mc = chunk * B_;                    // rows this chunk
        dim3 g1(Mc / 64, H_ / 64);
        gemm_xp<<<g1, 256, 0, stream>>>(sentence + (size_t)s0 * B_ * E_,
                                        W_ih, bias, xp);
        rnn_scan<<<64, 1024, 0, stream>>>(xp, W_hh, h, chunk);
    }
}

// Round 2
// 1927.994 us; speedup vs baseline: 1.0931x; 1.0931x over previous
//
#include <hip/hip_runtime.h>
#include <math.h>

#define S_TOT 2048
#define B_    64
#define E_    256
#define H_    256

// ---------------- Phase 1: xp = A @ W_ih + bias ----------------
__global__ __launch_bounds__(256) void gemm_xp(
    const float* __restrict__ A, const float* __restrict__ W,
    const float* __restrict__ bias, float* __restrict__ out)
{
    __shared__ float As[32][68];
    __shared__ float Bs[32][64];

    const int tid = threadIdx.x;
    const int bm = blockIdx.x * 64;
    const int bn = blockIdx.y * 64;
    const int tx = tid & 15;
    const int ty = tid >> 4;

    float acc[4][4] = {};

    const int ar = tid >> 3;
    const int ak = (tid & 7) << 2;
    const int br = tid >> 4;
    const int bc = (tid & 15) << 2;

    for (int k0 = 0; k0 < E_; k0 += 32) {
        float4 a0 = *(const float4*)&A[(size_t)(bm + ar)      * E_ + k0 + ak];
        float4 a1 = *(const float4*)&A[(size_t)(bm + ar + 32) * E_ + k0 + ak];
        float4 b0 = *(const float4*)&W[(size_t)(k0 + br)      * H_ + bn + bc];
        float4 b1 = *(const float4*)&W[(size_t)(k0 + br + 16) * H_ + bn + bc];

        As[ak+0][ar]    = a0.x; As[ak+1][ar]    = a0.y; As[ak+2][ar]    = a0.z; As[ak+3][ar]    = a0.w;
        As[ak+0][ar+32] = a1.x; As[ak+1][ar+32] = a1.y; As[ak+2][ar+32] = a1.z; As[ak+3][ar+32] = a1.w;
        *(float4*)&Bs[br][bc]      = b0;
        *(float4*)&Bs[br + 16][bc] = b1;
        __syncthreads();

        #pragma unroll
        for (int kk = 0; kk < 32; kk++) {
            const float4 av = *(const float4*)&As[kk][ty << 2];
            const float4 bv = *(const float4*)&Bs[kk][tx << 2];
            acc[0][0] += av.x*bv.x; acc[0][1] += av.x*bv.y; acc[0][2] += av.x*bv.z; acc[0][3] += av.x*bv.w;
            acc[1][0] += av.y*bv.x; acc[1][1] += av.y*bv.y; acc[1][2] += av.y*bv.z; acc[1][3] += av.y*bv.w;
            acc[2][0] += av.z*bv.x; acc[2][1] += av.z*bv.y; acc[2][2] += av.z*bv.z; acc[2][3] += av.z*bv.w;
            acc[3][0] += av.w*bv.x; acc[3][1] += av.w*bv.y; acc[3][2] += av.w*bv.z; acc[3][3] += av.w*bv.w;
        }
        __syncthreads();
    }

    const float4 bb = *(const float4*)&bias[bn + (tx << 2)];
    #pragma unroll
    for (int i = 0; i < 4; i++) {
        float4 o;
        o.x = acc[i][0] + bb.x;
        o.y = acc[i][1] + bb.y;
        o.z = acc[i][2] + bb.z;
        o.w = acc[i][3] + bb.w;
        *(float4*)&out[(size_t)(bm + (ty << 2) + i) * H_ + bn + (tx << 2)] = o;
    }
}

// ---------------- Phase 2: sequential scan, one workgroup per batch ----------
// 512 threads: thread t -> (g = t>>2 owns outputs j=2g,2g+1 ; kq = t&3 owns
// k in [kq*64, kq*64+64)).  W slice (128 floats) in registers; h ping-pong in
// LDS with 68-float segments (4-float pad -> 4 kq addresses hit disjoint
// banks, conflict-free multicast).  Quad shuffle-reduce; ONE barrier/step.
__global__ __launch_bounds__(512, 2) void rnn_scan(
    const float* __restrict__ xp,    // [steps, B, H]
    const float* __restrict__ Whh,   // [H, H]
    float* __restrict__ h,           // [B, H] persistent state (= d_out)
    int steps)
{
    __shared__ float hbuf[2][4 * 68];   // [pingpong][segment kq][64 + 4 pad]

    const int b  = blockIdx.x;
    const int t  = threadIdx.x;
    const int kq = t & 3;
    const int g  = t >> 2;           // 0..127
    const int j0 = g << 1;           // output pair

    // w[i] = (Whh[kq*64+i][j0], Whh[kq*64+i][j0+1])  -- coalesced float2 loads
    float2 w[64];
    #pragma unroll
    for (int i = 0; i < 64; i++)
        w[i] = *(const float2*)&Whh[(size_t)(kq * 64 + i) * H_ + j0];

    if (t < H_) hbuf[0][(t >> 6) * 68 + (t & 63)] = h[b * H_ + t];
    float2 xpn = make_float2(0.f, 0.f);
    if (kq == 0) xpn = *(const float2*)&xp[(size_t)b * H_ + j0];
    __syncthreads();

    int p = 0;
    for (int s = 0; s < steps; s++) {
        const float2 xpc = xpn;
        if (kq == 0 && s + 1 < steps)
            xpn = *(const float2*)&xp[((size_t)(s + 1) * B_ + b) * H_ + j0];

        const float4* hv = (const float4*)&hbuf[p][kq * 68];
        float a0 = 0.f, a1 = 0.f;
        #pragma unroll
        for (int i = 0; i < 16; i++) {
            const float4 h4 = hv[i];
            const float2 w0 = w[4*i+0], w1 = w[4*i+1], w2 = w[4*i+2], w3 = w[4*i+3];
            a0 += h4.x*w0.x + h4.y*w1.x + h4.z*w2.x + h4.w*w3.x;
            a1 += h4.x*w0.y + h4.y*w1.y + h4.z*w2.y + h4.w*w3.y;
        }
        // reduce across the 4 kq lanes of each quad (intra-wave, no LDS)
        a0 += __shfl_xor(a0, 1); a0 += __shfl_xor(a0, 2);
        a1 += __shfl_xor(a1, 1); a1 += __shfl_xor(a1, 2);

        if (kq == 0) {
            const float v0 = xpc.x + a0, v1 = xpc.y + a1;
            const float e0 = __expf(2.f * v0), e1 = __expf(2.f * v1);
            float2 hn;
            hn.x = 1.f - 2.f / (e0 + 1.f);
            hn.y = 1.f - 2.f / (e1 + 1.f);
            *(float2*)&hbuf[p ^ 1][(j0 >> 6) * 68 + (j0 & 63)] = hn;
        }
        __syncthreads();
        p ^= 1;
    }

    if (t < H_) h[b * H_ + t] = hbuf[p][(t >> 6) * 68 + (t & 63)];
}

extern "C" void kernel_launch(void* const* d_in, const int* in_sizes, int n_in,
                              void* d_out, int out_size, void* d_ws, size_t ws_size,
                              hipStream_t stream)
{
    const float* sentence = (const float*)d_in[0];  // [S,B,E]
    const float* h0       = (const float*)d_in[1];  // [B,H]
    const float* W_ih     = (const float*)d_in[2];  // [E,H]
    const float* W_hh     = (const float*)d_in[3];  // [H,H]
    const float* bias     = (const float*)d_in[4];  // [H]
    float* h  = (float*)d_out;
    float* xp = (float*)d_ws;

    int chunk = 512;   // 512*64*256*4 = 33.5 MB
    while ((size_t)chunk * B_ * H_ * sizeof(float) > ws_size && chunk > 64)
        chunk >>= 1;

    hipMemcpyAsync(h, h0, B_ * H_ * sizeof(float), hipMemcpyDeviceToDevice, stream);

    for (int s0 = 0; s0 < S_TOT; s0 += chunk) {
        const int Mc = chunk * B_;
        dim3 g1(Mc / 64, H_ / 64);
        gemm_xp<<<g1, 256, 0, stream>>>(sentence + (size_t)s0 * B_ * E_,
                                        W_ih, bias, xp);
        rnn_scan<<<64, 512, 0, stream>>>(xp, W_hh, h, chunk);
    }
}